// Round 15
// baseline (420.140 us; speedup 1.0000x reference)
//
#include <hip/hip_runtime.h>
#include <hip/hip_bf16.h>

typedef __attribute__((ext_vector_type(4))) float f32x4;
typedef __attribute__((ext_vector_type(8))) short s16x8;
typedef unsigned short ushort_t;

#define N_DIM 4096
#define C_DIM 512

#if __has_builtin(__builtin_amdgcn_exp2f)
#define EXP2(x) __builtin_amdgcn_exp2f(x)
#else
#define EXP2(x) exp2f(x)
#endif

static __device__ __forceinline__ unsigned short f2bf(float f) {
    union { float f; unsigned u; } v; v.f = f;
    unsigned r = v.u + 0x7FFFu + ((v.u >> 16) & 1u);
    return (unsigned short)(r >> 16);
}

// ---------------- GroupNorm stats
__global__ void gn_stats_kernel(const float* __restrict__ x, float* __restrict__ stats) {
    int bg = blockIdx.x;
    int b = bg >> 5, g = bg & 31;
    const float* base = x + (size_t)b * (N_DIM * C_DIM) + g * 16;
    float sum = 0.f, ss = 0.f;
    for (int n = threadIdx.x; n < N_DIM; n += 256) {
        const float4* p = (const float4*)(base + (size_t)n * C_DIM);
        #pragma unroll
        for (int t = 0; t < 4; ++t) {
            float4 v = p[t];
            sum += v.x + v.y + v.z + v.w;
            ss  += v.x*v.x + v.y*v.y + v.z*v.z + v.w*v.w;
        }
    }
    #pragma unroll
    for (int o = 32; o > 0; o >>= 1) {
        sum += __shfl_down(sum, o);
        ss  += __shfl_down(ss, o);
    }
    __shared__ float red[8];
    int wid = threadIdx.x >> 6, lane = threadIdx.x & 63;
    if (lane == 0) { red[wid*2] = sum; red[wid*2+1] = ss; }
    __syncthreads();
    if (threadIdx.x == 0) {
        sum = red[0]+red[2]+red[4]+red[6];
        ss  = red[1]+red[3]+red[5]+red[7];
        float mean = sum * (1.f/65536.f);
        float var  = ss  * (1.f/65536.f) - mean*mean;
        stats[bg*2]   = mean;
        stats[bg*2+1] = rsqrtf(var + 1e-5f);
    }
}

// ---------------- normalize + gamma/beta + cast to bf16
__global__ void gn_norm_kernel(const float* __restrict__ x, const float* __restrict__ gamma,
                               const float* __restrict__ beta, const float* __restrict__ stats,
                               ushort_t* __restrict__ xn) {
    size_t i = ((size_t)blockIdx.x * 256 + threadIdx.x) * 4;
    int c = (int)(i & 511);
    int b = (int)(i >> 21);
    int bg = b*32 + (c >> 4);
    float mean = stats[bg*2], rstd = stats[bg*2+1];
    float4 v  = *(const float4*)(x + i);
    float4 ga = *(const float4*)(gamma + c);
    float4 be = *(const float4*)(beta + c);
    ushort4 o;
    o.x = f2bf((v.x - mean) * rstd * ga.x + be.x);
    o.y = f2bf((v.y - mean) * rstd * ga.y + be.y);
    o.z = f2bf((v.z - mean) * rstd * ga.z + be.z);
    o.w = f2bf((v.w - mean) * rstd * ga.w + be.w);
    *(ushort4*)(xn + i) = o;
}

// ---------------- weights: fp32 [Cin][Cout] -> bf16 transposed [Cout][Cin], 4 mats
__global__ void wconv_kernel(const float* __restrict__ wq, const float* __restrict__ wk,
                             const float* __restrict__ wv, const float* __restrict__ wp,
                             ushort_t* __restrict__ wt) {
    int idx = blockIdx.x * 256 + threadIdx.x;
    int m = idx >> 18;
    int r = idx & 262143;
    int ci = r >> 9, co = r & 511;
    const float* w = (m == 0) ? wq : (m == 1) ? wk : (m == 2) ? wv : wp;
    wt[(size_t)m * 262144 + (size_t)co * 512 + ci] = f2bf(w[(size_t)ci * 512 + co]);
}

// ---------------- QKV GEMM, m97-style 128x128 tile (verified R9-R14).
// q pre-scale folds C^-0.5 * log2(e) (exp2-domain softmax downstream).
__global__ __launch_bounds__(256) void qkv_kernel(const ushort_t* __restrict__ xn, const ushort_t* __restrict__ wt,
                         const float* __restrict__ bq, const float* __restrict__ bk, const float* __restrict__ bv,
                         ushort_t* __restrict__ q, ushort_t* __restrict__ k, ushort_t* __restrict__ v) {
    __shared__ char alds[2][8192];
    __shared__ char blds[2][8192];
    const int tid = threadIdx.x;
    const int w = tid >> 6, lane = tid & 63;
    const int lr = lane & 15, lg = lane >> 4;
    const int wr = w >> 1, wc = w & 1;
    const int m0 = blockIdx.x * 128;
    const int c0g = blockIdx.y * 128;
    const int z = c0g >> 9;
    const int c0 = c0g & 511;
    const ushort_t* W = wt + (size_t)z * 262144;
    const float* bias = (z == 0) ? bq : (z == 1) ? bk : bv;
    const float scale = (z == 0) ? 0.06376257818f : 1.0f;  // 512^-0.5 * log2(e)

    f32x4 acc[4][4];
    #pragma unroll
    for (int a = 0; a < 4; ++a)
        #pragma unroll
        for (int b = 0; b < 4; ++b) acc[a][b] = (f32x4){0.f,0.f,0.f,0.f};

    const int g1 = tid, g2 = tid + 256;
    const int r1 = g1 >> 2, s1 = ((g1 & 3) ^ (r1 & 3)) << 4;
    const int r2g = g2 >> 2, s2 = ((g2 & 3) ^ (r2g & 3)) << 4;

    auto STAGE = [&](int buf, int k0) {
        const char* A = (const char*)xn + (size_t)(m0) * 1024 + k0 * 2;
        const char* B = (const char*)W + (size_t)(c0) * 1024 + k0 * 2;
        __builtin_amdgcn_global_load_lds((const __attribute__((address_space(1))) void*)(A + (size_t)r1 * 1024 + s1),
            (__attribute__((address_space(3))) void*)(&alds[buf][g1 * 16]), 16, 0, 0);
        __builtin_amdgcn_global_load_lds((const __attribute__((address_space(1))) void*)(A + (size_t)r2g * 1024 + s2),
            (__attribute__((address_space(3))) void*)(&alds[buf][g2 * 16]), 16, 0, 0);
        __builtin_amdgcn_global_load_lds((const __attribute__((address_space(1))) void*)(B + (size_t)r1 * 1024 + s1),
            (__attribute__((address_space(3))) void*)(&blds[buf][g1 * 16]), 16, 0, 0);
        __builtin_amdgcn_global_load_lds((const __attribute__((address_space(1))) void*)(B + (size_t)r2g * 1024 + s2),
            (__attribute__((address_space(3))) void*)(&blds[buf][g2 * 16]), 16, 0, 0);
    };

    STAGE(0, 0);
    for (int ks = 0; ks < 16; ++ks) {
        const int cur = ks & 1;
        if (ks < 15) {
            STAGE(cur ^ 1, (ks + 1) * 32);
            asm volatile("s_waitcnt vmcnt(4)" ::: "memory");
        } else {
            asm volatile("s_waitcnt vmcnt(0)" ::: "memory");
        }
        __builtin_amdgcn_s_barrier();
        asm volatile("" ::: "memory");
        s16x8 af[4], bf[4];
        #pragma unroll
        for (int mi = 0; mi < 4; ++mi) {
            int row = wr * 64 + mi * 16 + lr;
            af[mi] = *(const s16x8*)(&alds[cur][row * 64 + ((lg ^ (lr & 3)) << 4)]);
        }
        #pragma unroll
        for (int ni = 0; ni < 4; ++ni) {
            int row = wc * 64 + ni * 16 + lr;
            bf[ni] = *(const s16x8*)(&blds[cur][row * 64 + ((lg ^ (lr & 3)) << 4)]);
        }
        #pragma unroll
        for (int mi = 0; mi < 4; ++mi)
            #pragma unroll
            for (int ni = 0; ni < 4; ++ni)
                acc[mi][ni] = __builtin_amdgcn_mfma_f32_16x16x32_bf16(af[mi], bf[ni], acc[mi][ni], 0, 0, 0);
        asm volatile("" ::: "memory");
        __builtin_amdgcn_s_barrier();
    }

    if (z < 2) {
        ushort_t* out = (z == 0) ? q : k;
        #pragma unroll
        for (int ni = 0; ni < 4; ++ni) {
            int cg = c0 + wc * 64 + ni * 16 + lr;
            float bb = bias[cg];
            #pragma unroll
            for (int mi = 0; mi < 4; ++mi) {
                int row = m0 + wr * 64 + mi * 16 + lg * 4;
                #pragma unroll
                for (int r2 = 0; r2 < 4; ++r2)
                    out[(size_t)(row + r2) * 512 + cg] = f2bf((acc[mi][ni][r2] + bb) * scale);
            }
        }
    } else {
        #pragma unroll
        for (int ni = 0; ni < 4; ++ni) {
            int cg = c0 + wc * 64 + ni * 16 + lr;
            float bb = bias[cg];
            #pragma unroll
            for (int mi = 0; mi < 4; ++mi) {
                int row = m0 + wr * 64 + mi * 16 + lg * 4;
                int batch = row >> 12, j = row & 4095;
                ushort4 o;
                o.x = f2bf(acc[mi][ni][0] + bb);
                o.y = f2bf(acc[mi][ni][1] + bb);
                o.z = f2bf(acc[mi][ni][2] + bb);
                o.w = f2bf(acc[mi][ni][3] + bb);
                *(ushort4*)(v + (size_t)batch * (512*4096) + (size_t)cg * 4096 + j) = o;
            }
        }
    }
}

// ---------------- flash attention, producer/consumer wave specialization:
// 8 waves (2/SIMD). Waves 0-3 (producers): QK^T + softmax + P publish for row-group rg
// (qf + softmax state, NO acc). Waves 4-7 (consumers): rescale + PV for 128-channel
// slice rg across all 64 rows (acc 128 regs, NO qf). Each SIMD = 1 producer + 1
// consumer -> consumer's independent PV MFMAs fill the producer's serial QK/softmax
// chain. Producers stage K, consumers stage V. R14 swizzles/pipeline/exp2 kept.
__global__ __launch_bounds__(512) void attn_kernel(const ushort_t* __restrict__ q, const ushort_t* __restrict__ k,
                          const ushort_t* __restrict__ vt, ushort_t* __restrict__ O) {
    __shared__ char slds[131072 + 8192 + 512];  // 2x(K32K|V32K) | plds x2 | rlds x2
    char* plds = slds + 131072;
    float* rlds = (float*)(slds + 131072 + 8192);
    const int tid = threadIdx.x;
    const int w = tid >> 6, lane = tid & 63;
    const int lr = lane & 15, lg = lane >> 4;
    const bool isA = (w < 4);       // producer
    const int rg = w & 3;           // producer: row-group; consumer: channel-group
    const int batch = blockIdx.y;
    const int i0 = blockIdx.x * 64;
    const char* kb = (const char*)(k  + (size_t)batch * (4096 * 512));
    const char* vb = (const char*)(vt + (size_t)batch * (512 * 4096));
    const ushort_t* qb = q + (size_t)batch * (4096 * 512);

    // producer state
    s16x8 qf[16];
    if (isA) {
        const ushort_t* qrow = qb + (size_t)(i0 + rg * 16 + lr) * 512 + lg * 8;
        #pragma unroll
        for (int t = 0; t < 16; ++t) qf[t] = *(const s16x8*)(qrow + t * 32);
    }
    float m = -1e30f, s = 0.f;

    // consumer state
    f32x4 acc[8][4];
    #pragma unroll
    for (int a = 0; a < 8; ++a)
        #pragma unroll
        for (int b = 0; b < 4; ++b) acc[a][b] = (f32x4){0.f,0.f,0.f,0.f};

    // hoisted per-lane LDS bases (R14-verified address sets)
    const int kbase_e = lr * 1024 + ((lg ^ (lr & 3)) << 4) + (((lr >> 2) & 1) << 6);
    const int kbase_o = kbase_e ^ 64;
    const int vread_off = 32768 + rg * 8192 + lr * 64 + ((lg ^ ((lr >> 1) & 3)) << 4); // + ct*1024
    const int pread_off = lr * 64 + ((lg ^ (lr & 3)) << 4);                            // + g*1024
    const int vswz = ((lane & 3) ^ ((lane >> 3) & 3)) << 4;

    auto STAGE_K = [&](int buf, int j0) {   // producers: 8 rows each
        char* lb = slds + buf * 65536;
        const char* gk = kb + (size_t)j0 * 1024;
        #pragma unroll
        for (int r = 0; r < 8; ++r) {
            int row = rg * 8 + r;           // row&7 == r (8-slot involution, rule 21)
            __builtin_amdgcn_global_load_lds(
                (const __attribute__((address_space(1))) void*)(gk + (size_t)row * 1024 + ((lane ^ r) << 4)),
                (__attribute__((address_space(3))) void*)(lb + row * 1024), 16, 0, 0);
        }
    };
    auto STAGE_V = [&](int buf, int j0) {   // consumers: 8 p-rows each
        char* lv = slds + buf * 65536 + 32768;
        const char* gv = vb + (size_t)j0 * 2;
        #pragma unroll
        for (int r = 0; r < 8; ++r) {
            int p = rg * 8 + r;
            int c = p * 16 + (lane >> 2);
            __builtin_amdgcn_global_load_lds(
                (const __attribute__((address_space(1))) void*)(gv + (size_t)c * 8192 + vswz),
                (__attribute__((address_space(3))) void*)(lv + p * 1024), 16, 0, 0);
        }
    };

    auto QKSM = [&](int buf, int pbuf) {
        const char* ke = slds + buf * 65536 + kbase_e;
        const char* ko = slds + buf * 65536 + kbase_o;
        f32x4 sa = {0,0,0,0}, sb = {0,0,0,0}, sc2 = {0,0,0,0}, sd = {0,0,0,0};
        #pragma unroll
        for (int tt = 0; tt < 16; tt += 2) {
            const int off = (tt >> 1) * 128;
            s16x8 k0f = *(const s16x8*)(ke + off);
            s16x8 k1f = *(const s16x8*)(ko + off);
            s16x8 k2f = *(const s16x8*)(ke + 16384 + off);
            s16x8 k3f = *(const s16x8*)(ko + 16384 + off);
            sa  = __builtin_amdgcn_mfma_f32_16x16x32_bf16(k0f, qf[tt],   sa,  0,0,0);
            sb  = __builtin_amdgcn_mfma_f32_16x16x32_bf16(k1f, qf[tt+1], sb,  0,0,0);
            sc2 = __builtin_amdgcn_mfma_f32_16x16x32_bf16(k2f, qf[tt],   sc2, 0,0,0);
            sd  = __builtin_amdgcn_mfma_f32_16x16x32_bf16(k3f, qf[tt+1], sd,  0,0,0);
        }
        f32x4 s1 = sa + sb;   // log2-domain scores
        f32x4 s2 = sc2 + sd;

        float m01 = fmaxf(fmaxf(s1[0], s1[1]), s1[2]);
        float m02 = fmaxf(fmaxf(s1[3], s2[0]), s2[1]);
        float m03 = fmaxf(fmaxf(s2[2], s2[3]), m01);
        float tm = fmaxf(m02, m03);
        tm = fmaxf(tm, __shfl_xor(tm, 16));
        tm = fmaxf(tm, __shfl_xor(tm, 32));
        float resc = 1.f;
        if (!__all(tm <= m + 11.0f)) {      // defer-max, log2 units
            float mnew = fmaxf(m, tm);
            resc = EXP2(m - mnew);
            s *= resc;
            m = mnew;
        }
        f32x4 p1, p2;
        #pragma unroll
        for (int r2 = 0; r2 < 4; ++r2) { p1[r2] = EXP2(s1[r2] - m); p2[r2] = EXP2(s2[r2] - m); }
        float t0 = (p1[0] + p1[1]) + (p1[2] + p1[3]);
        float t1 = (p2[0] + p2[1]) + (p2[2] + p2[3]);
        float ts = t0 + t1;
        ts += __shfl_xor(ts, 16);
        ts += __shfl_xor(ts, 32);
        s += ts;

        unsigned w0 = (unsigned)f2bf(p1[0]) | ((unsigned)f2bf(p1[1]) << 16);
        unsigned w1 = (unsigned)f2bf(p1[2]) | ((unsigned)f2bf(p1[3]) << 16);
        unsigned w2 = (unsigned)f2bf(p2[0]) | ((unsigned)f2bf(p2[1]) << 16);
        unsigned w3 = (unsigned)f2bf(p2[2]) | ((unsigned)f2bf(p2[3]) << 16);
        char* prow = plds + pbuf * 4096 + rg * 1024 + lr * 64 + ((lg & 1) << 3);
        *(uint2*)(prow + ((((lg >> 1)    ) ^ (lr & 3)) << 4)) = (uint2){w0, w1};
        *(uint2*)(prow + (((2 | (lg >> 1)) ^ (lr & 3)) << 4)) = (uint2){w2, w3};
        if (lg == 0) rlds[pbuf * 64 + rg * 16 + lr] = resc;
    };

    // prologue: producers stage K(0)->buf0, K(1)->buf1; consumers stage V(0)->buf0
    if (isA) { STAGE_K(0, 0); STAGE_K(1, 32); }
    else     { STAGE_V(0, 0); }
    asm volatile("s_waitcnt vmcnt(0)" ::: "memory");
    __builtin_amdgcn_s_barrier();
    asm volatile("" ::: "memory");
    if (isA) QKSM(0, 0);
    asm volatile("s_waitcnt lgkmcnt(0)" ::: "memory");
    __builtin_amdgcn_s_barrier();
    asm volatile("" ::: "memory");

    for (int t = 0; t < 128; ++t) {
        const int cur = t & 1, nxt = cur ^ 1;
        if (isA) {
            // producer: stage K(t+2) into buf[cur], then QK(t+1)+softmax+P(t+1) publish
            if (t < 126) STAGE_K(cur, (t + 2) * 32);
            if (t < 127) QKSM(nxt, nxt);
        } else {
            // consumer: stage V(t+1) into buf[nxt], then rescale + PV(t)
            if (t < 127) STAGE_V(nxt, (t + 1) * 32);
            {
                const float* rr = rlds + cur * 64;
                float rf0 = rr[lr], rf1 = rr[16 + lr], rf2 = rr[32 + lr], rf3 = rr[48 + lr];
                if (__any(rf0 != 1.f || rf1 != 1.f || rf2 != 1.f || rf3 != 1.f)) {
                    #pragma unroll
                    for (int ct = 0; ct < 8; ++ct) {
                        acc[ct][0] *= rf0; acc[ct][1] *= rf1; acc[ct][2] *= rf2; acc[ct][3] *= rf3;
                    }
                }
            }
            const char* pb = plds + cur * 4096 + pread_off;
            s16x8 pf[4];
            #pragma unroll
            for (int g = 0; g < 4; ++g)
                pf[g] = *(const s16x8*)(pb + g * 1024);

            const char* vl = slds + cur * 65536 + vread_off;
            #pragma unroll
            for (int ct = 0; ct < 8; ++ct) {
                s16x8 vf = *(const s16x8*)(vl + ct * 1024);
                #pragma unroll
                for (int g = 0; g < 4; ++g)
                    acc[ct][g] = __builtin_amdgcn_mfma_f32_16x16x32_bf16(vf, pf[g], acc[ct][g], 0,0,0);
            }
        }

        asm volatile("s_waitcnt vmcnt(0) lgkmcnt(0)" ::: "memory");
        __builtin_amdgcn_s_barrier();
        asm volatile("" ::: "memory");
    }

    // producers publish 1/s; consumers write O
    if (isA && lg == 0) rlds[rg * 16 + lr] = 1.f / s;
    __syncthreads();
    if (!isA) {
        float inv0 = rlds[lr], inv1 = rlds[16 + lr], inv2 = rlds[32 + lr], inv3 = rlds[48 + lr];
        #pragma unroll
        for (int ct = 0; ct < 8; ++ct) {
            #pragma unroll
            for (int g = 0; g < 4; ++g) {
                float iv = (g == 0) ? inv0 : (g == 1) ? inv1 : (g == 2) ? inv2 : inv3;
                ushort4 o;
                o.x = f2bf(acc[ct][g][0] * iv);
                o.y = f2bf(acc[ct][g][1] * iv);
                o.z = f2bf(acc[ct][g][2] * iv);
                o.w = f2bf(acc[ct][g][3] * iv);
                *(ushort4*)(O + ((size_t)batch * 4096 + i0 + g*16 + lr) * 512
                            + rg * 128 + ct * 16 + lg * 4) = o;
            }
        }
    }
}

// ---------------- final projection, m97-style 128x128 tile + bias + residual (fp32 out)
__global__ __launch_bounds__(256) void proj_kernel(const ushort_t* __restrict__ O, const ushort_t* __restrict__ wt,
                          const float* __restrict__ bp, const float* __restrict__ x, float* __restrict__ out) {
    __shared__ char alds[2][8192];
    __shared__ char blds[2][8192];
    const int tid = threadIdx.x;
    const int w = tid >> 6, lane = tid & 63;
    const int lr = lane & 15, lg = lane >> 4;
    const int wr = w >> 1, wc = w & 1;
    const int m0 = blockIdx.x * 128;
    const int c0 = blockIdx.y * 128;
    const ushort_t* W = wt + (size_t)3 * 262144;

    f32x4 acc[4][4];
    #pragma unroll
    for (int a = 0; a < 4; ++a)
        #pragma unroll
        for (int b = 0; b < 4; ++b) acc[a][b] = (f32x4){0.f,0.f,0.f,0.f};

    const int g1 = tid, g2 = tid + 256;
    const int r1 = g1 >> 2, s1 = ((g1 & 3) ^ (r1 & 3)) << 4;
    const int r2g = g2 >> 2, s2 = ((g2 & 3) ^ (r2g & 3)) << 4;

    auto STAGE = [&](int buf, int k0) {
        const char* A = (const char*)O + (size_t)(m0) * 1024 + k0 * 2;
        const char* B = (const char*)W + (size_t)(c0) * 1024 + k0 * 2;
        __builtin_amdgcn_global_load_lds((const __attribute__((address_space(1))) void*)(A + (size_t)r1 * 1024 + s1),
            (__attribute__((address_space(3))) void*)(&alds[buf][g1 * 16]), 16, 0, 0);
        __builtin_amdgcn_global_load_lds((const __attribute__((address_space(1))) void*)(A + (size_t)r2g * 1024 + s2),
            (__attribute__((address_space(3))) void*)(&alds[buf][g2 * 16]), 16, 0, 0);
        __builtin_amdgcn_global_load_lds((const __attribute__((address_space(1))) void*)(B + (size_t)r1 * 1024 + s1),
            (__attribute__((address_space(3))) void*)(&blds[buf][g1 * 16]), 16, 0, 0);
        __builtin_amdgcn_global_load_lds((const __attribute__((address_space(1))) void*)(B + (size_t)r2g * 1024 + s2),
            (__attribute__((address_space(3))) void*)(&blds[buf][g2 * 16]), 16, 0, 0);
    };

    STAGE(0, 0);
    for (int ks = 0; ks < 16; ++ks) {
        const int cur = ks & 1;
        if (ks < 15) {
            STAGE(cur ^ 1, (ks + 1) * 32);
            asm volatile("s_waitcnt vmcnt(4)" ::: "memory");
        } else {
            asm volatile("s_waitcnt vmcnt(0)" ::: "memory");
        }
        __builtin_amdgcn_s_barrier();
        asm volatile("" ::: "memory");
        s16x8 af[4], bf[4];
        #pragma unroll
        for (int mi = 0; mi < 4; ++mi) {
            int row = wr * 64 + mi * 16 + lr;
            af[mi] = *(const s16x8*)(&alds[cur][row * 64 + ((lg ^ (lr & 3)) << 4)]);
        }
        #pragma unroll
        for (int ni = 0; ni < 4; ++ni) {
            int row = wc * 64 + ni * 16 + lr;
            bf[ni] = *(const s16x8*)(&blds[cur][row * 64 + ((lg ^ (lr & 3)) << 4)]);
        }
        #pragma unroll
        for (int mi = 0; mi < 4; ++mi)
            #pragma unroll
            for (int ni = 0; ni < 4; ++ni)
                acc[mi][ni] = __builtin_amdgcn_mfma_f32_16x16x32_bf16(af[mi], bf[ni], acc[mi][ni], 0, 0, 0);
        asm volatile("" ::: "memory");
        __builtin_amdgcn_s_barrier();
    }

    #pragma unroll
    for (int ni = 0; ni < 4; ++ni) {
        int cg = c0 + wc * 64 + ni * 16 + lr;
        float bb = bp[cg];
        #pragma unroll
        for (int mi = 0; mi < 4; ++mi) {
            int row = m0 + wr * 64 + mi * 16 + lg * 4;
            #pragma unroll
            for (int r2 = 0; r2 < 4; ++r2) {
                size_t idx = (size_t)(row + r2) * 512 + cg;
                out[idx] = acc[mi][ni][r2] + bb + x[idx];
            }
        }
    }
}

extern "C" void kernel_launch(void* const* d_in, const int* in_sizes, int n_in,
                              void* d_out, int out_size, void* d_ws, size_t ws_size,
                              hipStream_t stream) {
    (void)in_sizes; (void)n_in; (void)out_size; (void)ws_size;
    const float* x     = (const float*)d_in[0];
    const float* gamma = (const float*)d_in[1];
    const float* beta  = (const float*)d_in[2];
    const float* wq    = (const float*)d_in[3];
    const float* bq    = (const float*)d_in[4];
    const float* wk    = (const float*)d_in[5];
    const float* bk    = (const float*)d_in[6];
    const float* wv    = (const float*)d_in[7];
    const float* bv    = (const float*)d_in[8];
    const float* wp    = (const float*)d_in[9];
    const float* bp    = (const float*)d_in[10];
    float* out = (float*)d_out;

    char* ws = (char*)d_ws;
    ushort_t* wt    = (ushort_t*)(ws);                 // 2 MB
    float*    stats = (float*)(ws + (2ull<<20));       // 1 KB
    ushort_t* xn    = (ushort_t*)(ws + (4ull<<20));    // 16 MB
    ushort_t* qb    = (ushort_t*)(ws + (20ull<<20));   // 16 MB
    ushort_t* kb    = (ushort_t*)(ws + (36ull<<20));   // 16 MB
    ushort_t* vt    = (ushort_t*)(ws + (52ull<<20));   // 16 MB
    ushort_t* Ob    = (ushort_t*)(ws + (68ull<<20));   // 16 MB

    hipLaunchKernelGGL(wconv_kernel,    dim3(4096),       dim3(256), 0, stream, wq, wk, wv, wp, wt);
    hipLaunchKernelGGL(gn_stats_kernel, dim3(128),        dim3(256), 0, stream, x, stats);
    hipLaunchKernelGGL(gn_norm_kernel,  dim3(8192),       dim3(256), 0, stream, x, gamma, beta, stats, xn);
    hipLaunchKernelGGL(qkv_kernel,      dim3(128, 12),    dim3(256), 0, stream, xn, wt, bq, bk, bv, qb, kb, vt);
    hipLaunchKernelGGL(attn_kernel,     dim3(64, 4),      dim3(512), 0, stream, qb, kb, vt, Ob);
    hipLaunchKernelGGL(proj_kernel,     dim3(128, 4),     dim3(256), 0, stream, Ob, wt, bp, x, out);
}

// Round 16
// 381.524 us; speedup vs baseline: 1.1012x; 1.1012x over previous
//
#include <hip/hip_runtime.h>
#include <hip/hip_bf16.h>

typedef __attribute__((ext_vector_type(4))) float f32x4;
typedef __attribute__((ext_vector_type(8))) short s16x8;
typedef unsigned short ushort_t;

#define N_DIM 4096
#define C_DIM 512

#if __has_builtin(__builtin_amdgcn_exp2f)
#define EXP2(x) __builtin_amdgcn_exp2f(x)
#else
#define EXP2(x) exp2f(x)
#endif

static __device__ __forceinline__ unsigned short f2bf(float f) {
    union { float f; unsigned u; } v; v.f = f;
    unsigned r = v.u + 0x7FFFu + ((v.u >> 16) & 1u);
    return (unsigned short)(r >> 16);
}

// ---------------- GroupNorm stats
__global__ void gn_stats_kernel(const float* __restrict__ x, float* __restrict__ stats) {
    int bg = blockIdx.x;
    int b = bg >> 5, g = bg & 31;
    const float* base = x + (size_t)b * (N_DIM * C_DIM) + g * 16;
    float sum = 0.f, ss = 0.f;
    for (int n = threadIdx.x; n < N_DIM; n += 256) {
        const float4* p = (const float4*)(base + (size_t)n * C_DIM);
        #pragma unroll
        for (int t = 0; t < 4; ++t) {
            float4 v = p[t];
            sum += v.x + v.y + v.z + v.w;
            ss  += v.x*v.x + v.y*v.y + v.z*v.z + v.w*v.w;
        }
    }
    #pragma unroll
    for (int o = 32; o > 0; o >>= 1) {
        sum += __shfl_down(sum, o);
        ss  += __shfl_down(ss, o);
    }
    __shared__ float red[8];
    int wid = threadIdx.x >> 6, lane = threadIdx.x & 63;
    if (lane == 0) { red[wid*2] = sum; red[wid*2+1] = ss; }
    __syncthreads();
    if (threadIdx.x == 0) {
        sum = red[0]+red[2]+red[4]+red[6];
        ss  = red[1]+red[3]+red[5]+red[7];
        float mean = sum * (1.f/65536.f);
        float var  = ss  * (1.f/65536.f) - mean*mean;
        stats[bg*2]   = mean;
        stats[bg*2+1] = rsqrtf(var + 1e-5f);
    }
}

// ---------------- normalize + gamma/beta + cast to bf16
__global__ void gn_norm_kernel(const float* __restrict__ x, const float* __restrict__ gamma,
                               const float* __restrict__ beta, const float* __restrict__ stats,
                               ushort_t* __restrict__ xn) {
    size_t i = ((size_t)blockIdx.x * 256 + threadIdx.x) * 4;
    int c = (int)(i & 511);
    int b = (int)(i >> 21);
    int bg = b*32 + (c >> 4);
    float mean = stats[bg*2], rstd = stats[bg*2+1];
    float4 v  = *(const float4*)(x + i);
    float4 ga = *(const float4*)(gamma + c);
    float4 be = *(const float4*)(beta + c);
    ushort4 o;
    o.x = f2bf((v.x - mean) * rstd * ga.x + be.x);
    o.y = f2bf((v.y - mean) * rstd * ga.y + be.y);
    o.z = f2bf((v.z - mean) * rstd * ga.z + be.z);
    o.w = f2bf((v.w - mean) * rstd * ga.w + be.w);
    *(ushort4*)(xn + i) = o;
}

// ---------------- weights: fp32 [Cin][Cout] -> bf16 transposed [Cout][Cin], 4 mats
__global__ void wconv_kernel(const float* __restrict__ wq, const float* __restrict__ wk,
                             const float* __restrict__ wv, const float* __restrict__ wp,
                             ushort_t* __restrict__ wt) {
    int idx = blockIdx.x * 256 + threadIdx.x;
    int m = idx >> 18;
    int r = idx & 262143;
    int ci = r >> 9, co = r & 511;
    const float* w = (m == 0) ? wq : (m == 1) ? wk : (m == 2) ? wv : wp;
    wt[(size_t)m * 262144 + (size_t)co * 512 + ci] = f2bf(w[(size_t)ci * 512 + co]);
}

// ---------------- QKV GEMM, m97-style 128x128 tile (verified R9-R14).
// q pre-scale folds C^-0.5 * log2(e) (exp2-domain softmax downstream).
__global__ __launch_bounds__(256) void qkv_kernel(const ushort_t* __restrict__ xn, const ushort_t* __restrict__ wt,
                         const float* __restrict__ bq, const float* __restrict__ bk, const float* __restrict__ bv,
                         ushort_t* __restrict__ q, ushort_t* __restrict__ k, ushort_t* __restrict__ v) {
    __shared__ char alds[2][8192];
    __shared__ char blds[2][8192];
    const int tid = threadIdx.x;
    const int w = tid >> 6, lane = tid & 63;
    const int lr = lane & 15, lg = lane >> 4;
    const int wr = w >> 1, wc = w & 1;
    const int m0 = blockIdx.x * 128;
    const int c0g = blockIdx.y * 128;
    const int z = c0g >> 9;
    const int c0 = c0g & 511;
    const ushort_t* W = wt + (size_t)z * 262144;
    const float* bias = (z == 0) ? bq : (z == 1) ? bk : bv;
    const float scale = (z == 0) ? 0.06376257818f : 1.0f;  // 512^-0.5 * log2(e)

    f32x4 acc[4][4];
    #pragma unroll
    for (int a = 0; a < 4; ++a)
        #pragma unroll
        for (int b = 0; b < 4; ++b) acc[a][b] = (f32x4){0.f,0.f,0.f,0.f};

    const int g1 = tid, g2 = tid + 256;
    const int r1 = g1 >> 2, s1 = ((g1 & 3) ^ (r1 & 3)) << 4;
    const int r2g = g2 >> 2, s2 = ((g2 & 3) ^ (r2g & 3)) << 4;

    auto STAGE = [&](int buf, int k0) {
        const char* A = (const char*)xn + (size_t)(m0) * 1024 + k0 * 2;
        const char* B = (const char*)W + (size_t)(c0) * 1024 + k0 * 2;
        __builtin_amdgcn_global_load_lds((const __attribute__((address_space(1))) void*)(A + (size_t)r1 * 1024 + s1),
            (__attribute__((address_space(3))) void*)(&alds[buf][g1 * 16]), 16, 0, 0);
        __builtin_amdgcn_global_load_lds((const __attribute__((address_space(1))) void*)(A + (size_t)r2g * 1024 + s2),
            (__attribute__((address_space(3))) void*)(&alds[buf][g2 * 16]), 16, 0, 0);
        __builtin_amdgcn_global_load_lds((const __attribute__((address_space(1))) void*)(B + (size_t)r1 * 1024 + s1),
            (__attribute__((address_space(3))) void*)(&blds[buf][g1 * 16]), 16, 0, 0);
        __builtin_amdgcn_global_load_lds((const __attribute__((address_space(1))) void*)(B + (size_t)r2g * 1024 + s2),
            (__attribute__((address_space(3))) void*)(&blds[buf][g2 * 16]), 16, 0, 0);
    };

    STAGE(0, 0);
    for (int ks = 0; ks < 16; ++ks) {
        const int cur = ks & 1;
        if (ks < 15) {
            STAGE(cur ^ 1, (ks + 1) * 32);
            asm volatile("s_waitcnt vmcnt(4)" ::: "memory");
        } else {
            asm volatile("s_waitcnt vmcnt(0)" ::: "memory");
        }
        __builtin_amdgcn_s_barrier();
        asm volatile("" ::: "memory");
        s16x8 af[4], bf[4];
        #pragma unroll
        for (int mi = 0; mi < 4; ++mi) {
            int row = wr * 64 + mi * 16 + lr;
            af[mi] = *(const s16x8*)(&alds[cur][row * 64 + ((lg ^ (lr & 3)) << 4)]);
        }
        #pragma unroll
        for (int ni = 0; ni < 4; ++ni) {
            int row = wc * 64 + ni * 16 + lr;
            bf[ni] = *(const s16x8*)(&blds[cur][row * 64 + ((lg ^ (lr & 3)) << 4)]);
        }
        __builtin_amdgcn_s_setprio(1);
        #pragma unroll
        for (int mi = 0; mi < 4; ++mi)
            #pragma unroll
            for (int ni = 0; ni < 4; ++ni)
                acc[mi][ni] = __builtin_amdgcn_mfma_f32_16x16x32_bf16(af[mi], bf[ni], acc[mi][ni], 0, 0, 0);
        __builtin_amdgcn_s_setprio(0);
        asm volatile("" ::: "memory");
        __builtin_amdgcn_s_barrier();
    }

    if (z < 2) {
        ushort_t* out = (z == 0) ? q : k;
        #pragma unroll
        for (int ni = 0; ni < 4; ++ni) {
            int cg = c0 + wc * 64 + ni * 16 + lr;
            float bb = bias[cg];
            #pragma unroll
            for (int mi = 0; mi < 4; ++mi) {
                int row = m0 + wr * 64 + mi * 16 + lg * 4;
                #pragma unroll
                for (int r2 = 0; r2 < 4; ++r2)
                    out[(size_t)(row + r2) * 512 + cg] = f2bf((acc[mi][ni][r2] + bb) * scale);
            }
        }
    } else {
        #pragma unroll
        for (int ni = 0; ni < 4; ++ni) {
            int cg = c0 + wc * 64 + ni * 16 + lr;
            float bb = bias[cg];
            #pragma unroll
            for (int mi = 0; mi < 4; ++mi) {
                int row = m0 + wr * 64 + mi * 16 + lg * 4;
                int batch = row >> 12, j = row & 4095;
                ushort4 o;
                o.x = f2bf(acc[mi][ni][0] + bb);
                o.y = f2bf(acc[mi][ni][1] + bb);
                o.z = f2bf(acc[mi][ni][2] + bb);
                o.w = f2bf(acc[mi][ni][3] + bb);
                *(ushort4*)(v + (size_t)batch * (512*4096) + (size_t)cg * 4096 + j) = o;
            }
        }
    }
}

// ---------------- flash attention (R14 structure + T5 setprio around MFMA clusters).
// One barrier/iter; QKSM(t+1)-first; PV(t) second; R12 8-slot K swizzle via hoisted
// bases + imm offsets; exp2-domain softmax; max3/sum trees.
__global__ __launch_bounds__(256) void attn_kernel(const ushort_t* __restrict__ q, const ushort_t* __restrict__ k,
                          const ushort_t* __restrict__ vt, ushort_t* __restrict__ O) {
    __shared__ char slds[131072 + 8192 + 512];  // 2x(K32K|V32K) | plds x2 | rlds x2
    char* plds = slds + 131072;
    float* rlds = (float*)(slds + 131072 + 8192);
    const int tid = threadIdx.x;
    const int w = tid >> 6, lane = tid & 63;
    const int lr = lane & 15, lg = lane >> 4;
    const int batch = blockIdx.y;
    const int i0 = blockIdx.x * 64;
    const char* kb = (const char*)(k  + (size_t)batch * (4096 * 512));
    const char* vb = (const char*)(vt + (size_t)batch * (512 * 4096));
    const ushort_t* qb = q + (size_t)batch * (4096 * 512);

    s16x8 qf[16];
    {
        const ushort_t* qrow = qb + (size_t)(i0 + w * 16 + lr) * 512 + lg * 8;
        #pragma unroll
        for (int t = 0; t < 16; ++t) qf[t] = *(const s16x8*)(qrow + t * 32);
    }

    f32x4 acc[8][4];
    #pragma unroll
    for (int a = 0; a < 8; ++a)
        #pragma unroll
        for (int b = 0; b < 4; ++b) acc[a][b] = (f32x4){0.f,0.f,0.f,0.f};
    float m = -1e30f, s = 0.f;

    // hoisted per-lane LDS bases (R14-verified address sets)
    const int kbase_e = lr * 1024 + ((lg ^ (lr & 3)) << 4) + (((lr >> 2) & 1) << 6);
    const int kbase_o = kbase_e ^ 64;
    const int vread_off = 32768 + w * 8192 + lr * 64 + ((lg ^ ((lr >> 1) & 3)) << 4); // + ct*1024
    const int pread_off = lr * 64 + ((lg ^ (lr & 3)) << 4);                           // + g*1024
    const int vswz = ((lane & 3) ^ ((lane >> 3) & 3)) << 4;

    auto STAGE_K = [&](int buf, int j0) {
        char* lb = slds + buf * 65536;
        const char* gk = kb + (size_t)j0 * 1024;
        #pragma unroll
        for (int r = 0; r < 8; ++r) {
            int row = w * 8 + r;             // row&7 == r  (8-slot involution, rule 21)
            __builtin_amdgcn_global_load_lds(
                (const __attribute__((address_space(1))) void*)(gk + (size_t)row * 1024 + ((lane ^ r) << 4)),
                (__attribute__((address_space(3))) void*)(lb + row * 1024), 16, 0, 0);
        }
    };
    auto STAGE_V = [&](int buf, int j0) {
        char* lv = slds + buf * 65536 + 32768;
        const char* gv = vb + (size_t)j0 * 2;
        #pragma unroll
        for (int r = 0; r < 8; ++r) {
            int p = w * 8 + r;
            int c = p * 16 + (lane >> 2);
            __builtin_amdgcn_global_load_lds(
                (const __attribute__((address_space(1))) void*)(gv + (size_t)c * 8192 + vswz),
                (__attribute__((address_space(3))) void*)(lv + p * 1024), 16, 0, 0);
        }
    };

    auto QKSM = [&](int buf, int pbuf) {
        const char* ke = slds + buf * 65536 + kbase_e;
        const char* ko = slds + buf * 65536 + kbase_o;
        f32x4 sa = {0,0,0,0}, sb = {0,0,0,0}, sc2 = {0,0,0,0}, sd = {0,0,0,0};
        __builtin_amdgcn_s_setprio(1);
        #pragma unroll
        for (int tt = 0; tt < 16; tt += 2) {
            const int off = (tt >> 1) * 128;
            s16x8 k0f = *(const s16x8*)(ke + off);
            s16x8 k1f = *(const s16x8*)(ko + off);
            s16x8 k2f = *(const s16x8*)(ke + 16384 + off);
            s16x8 k3f = *(const s16x8*)(ko + 16384 + off);
            sa  = __builtin_amdgcn_mfma_f32_16x16x32_bf16(k0f, qf[tt],   sa,  0,0,0);
            sb  = __builtin_amdgcn_mfma_f32_16x16x32_bf16(k1f, qf[tt+1], sb,  0,0,0);
            sc2 = __builtin_amdgcn_mfma_f32_16x16x32_bf16(k2f, qf[tt],   sc2, 0,0,0);
            sd  = __builtin_amdgcn_mfma_f32_16x16x32_bf16(k3f, qf[tt+1], sd,  0,0,0);
        }
        __builtin_amdgcn_s_setprio(0);
        f32x4 s1 = sa + sb;   // log2-domain scores
        f32x4 s2 = sc2 + sd;

        float m01 = fmaxf(fmaxf(s1[0], s1[1]), s1[2]);
        float m02 = fmaxf(fmaxf(s1[3], s2[0]), s2[1]);
        float m03 = fmaxf(fmaxf(s2[2], s2[3]), m01);
        float tm = fmaxf(m02, m03);
        tm = fmaxf(tm, __shfl_xor(tm, 16));
        tm = fmaxf(tm, __shfl_xor(tm, 32));
        float resc = 1.f;
        if (!__all(tm <= m + 11.0f)) {       // defer-max, log2 units
            float mnew = fmaxf(m, tm);
            resc = EXP2(m - mnew);
            s *= resc;
            m = mnew;
        }
        f32x4 p1, p2;
        #pragma unroll
        for (int r2 = 0; r2 < 4; ++r2) { p1[r2] = EXP2(s1[r2] - m); p2[r2] = EXP2(s2[r2] - m); }
        float t0 = (p1[0] + p1[1]) + (p1[2] + p1[3]);
        float t1 = (p2[0] + p2[1]) + (p2[2] + p2[3]);
        float ts = t0 + t1;
        ts += __shfl_xor(ts, 16);
        ts += __shfl_xor(ts, 32);
        s += ts;

        unsigned w0 = (unsigned)f2bf(p1[0]) | ((unsigned)f2bf(p1[1]) << 16);
        unsigned w1 = (unsigned)f2bf(p1[2]) | ((unsigned)f2bf(p1[3]) << 16);
        unsigned w2 = (unsigned)f2bf(p2[0]) | ((unsigned)f2bf(p2[1]) << 16);
        unsigned w3 = (unsigned)f2bf(p2[2]) | ((unsigned)f2bf(p2[3]) << 16);
        char* prow = plds + pbuf * 4096 + w * 1024 + lr * 64 + ((lg & 1) << 3);
        *(uint2*)(prow + ((((lg >> 1)    ) ^ (lr & 3)) << 4)) = (uint2){w0, w1};
        *(uint2*)(prow + (((2 | (lg >> 1)) ^ (lr & 3)) << 4)) = (uint2){w2, w3};
        if (lg == 0) rlds[pbuf * 64 + w * 16 + lr] = resc;
    };

    // prologue: K(0),V(0) -> buf0; K(1) -> buf1; FULL drain
    STAGE_K(0, 0);
    STAGE_V(0, 0);
    STAGE_K(1, 32);
    asm volatile("s_waitcnt vmcnt(0)" ::: "memory");
    __builtin_amdgcn_s_barrier();
    asm volatile("" ::: "memory");
    QKSM(0, 0);
    asm volatile("s_waitcnt lgkmcnt(0)" ::: "memory");
    __builtin_amdgcn_s_barrier();
    asm volatile("" ::: "memory");

    for (int t = 0; t < 128; ++t) {
        const int cur = t & 1, nxt = cur ^ 1;
        if (t < 126) STAGE_K(cur, (t + 2) * 32);
        if (t < 127) STAGE_V(nxt, (t + 1) * 32);

        // QK(t+1) + softmax + P(t+1) publish FIRST (long serial chain starts early)
        if (t < 127) QKSM(nxt, nxt);

        // rescale + P fragments + PV(t)
        {
            const float* rr = rlds + cur * 64;
            float rf0 = rr[lr], rf1 = rr[16 + lr], rf2 = rr[32 + lr], rf3 = rr[48 + lr];
            if (__any(rf0 != 1.f || rf1 != 1.f || rf2 != 1.f || rf3 != 1.f)) {
                #pragma unroll
                for (int ct = 0; ct < 8; ++ct) {
                    acc[ct][0] *= rf0; acc[ct][1] *= rf1; acc[ct][2] *= rf2; acc[ct][3] *= rf3;
                }
            }
        }
        const char* pb = plds + cur * 4096 + pread_off;
        s16x8 pf[4];
        #pragma unroll
        for (int g = 0; g < 4; ++g)
            pf[g] = *(const s16x8*)(pb + g * 1024);

        const char* vl = slds + cur * 65536 + vread_off;
        __builtin_amdgcn_s_setprio(1);
        #pragma unroll
        for (int ct = 0; ct < 8; ++ct) {
            s16x8 vf = *(const s16x8*)(vl + ct * 1024);
            #pragma unroll
            for (int g = 0; g < 4; ++g)
                acc[ct][g] = __builtin_amdgcn_mfma_f32_16x16x32_bf16(vf, pf[g], acc[ct][g], 0,0,0);
        }
        __builtin_amdgcn_s_setprio(0);

        asm volatile("s_waitcnt vmcnt(0) lgkmcnt(0)" ::: "memory");
        __builtin_amdgcn_s_barrier();
        asm volatile("" ::: "memory");
    }

    // final 1/s exchange
    if (lg == 0) rlds[w * 16 + lr] = 1.f / s;
    __syncthreads();
    float inv0 = rlds[lr], inv1 = rlds[16 + lr], inv2 = rlds[32 + lr], inv3 = rlds[48 + lr];
    #pragma unroll
    for (int ct = 0; ct < 8; ++ct) {
        #pragma unroll
        for (int g = 0; g < 4; ++g) {
            float iv = (g == 0) ? inv0 : (g == 1) ? inv1 : (g == 2) ? inv2 : inv3;
            ushort4 o;
            o.x = f2bf(acc[ct][g][0] * iv);
            o.y = f2bf(acc[ct][g][1] * iv);
            o.z = f2bf(acc[ct][g][2] * iv);
            o.w = f2bf(acc[ct][g][3] * iv);
            *(ushort4*)(O + ((size_t)batch * 4096 + i0 + g*16 + lr) * 512
                        + w * 128 + ct * 16 + lg * 4) = o;
        }
    }
}

// ---------------- final projection, m97-style 128x128 tile + bias + residual (fp32 out)
__global__ __launch_bounds__(256) void proj_kernel(const ushort_t* __restrict__ O, const ushort_t* __restrict__ wt,
                          const float* __restrict__ bp, const float* __restrict__ x, float* __restrict__ out) {
    __shared__ char alds[2][8192];
    __shared__ char blds[2][8192];
    const int tid = threadIdx.x;
    const int w = tid >> 6, lane = tid & 63;
    const int lr = lane & 15, lg = lane >> 4;
    const int wr = w >> 1, wc = w & 1;
    const int m0 = blockIdx.x * 128;
    const int c0 = blockIdx.y * 128;
    const ushort_t* W = wt + (size_t)3 * 262144;

    f32x4 acc[4][4];
    #pragma unroll
    for (int a = 0; a < 4; ++a)
        #pragma unroll
        for (int b = 0; b < 4; ++b) acc[a][b] = (f32x4){0.f,0.f,0.f,0.f};

    const int g1 = tid, g2 = tid + 256;
    const int r1 = g1 >> 2, s1 = ((g1 & 3) ^ (r1 & 3)) << 4;
    const int r2g = g2 >> 2, s2 = ((g2 & 3) ^ (r2g & 3)) << 4;

    auto STAGE = [&](int buf, int k0) {
        const char* A = (const char*)O + (size_t)(m0) * 1024 + k0 * 2;
        const char* B = (const char*)W + (size_t)(c0) * 1024 + k0 * 2;
        __builtin_amdgcn_global_load_lds((const __attribute__((address_space(1))) void*)(A + (size_t)r1 * 1024 + s1),
            (__attribute__((address_space(3))) void*)(&alds[buf][g1 * 16]), 16, 0, 0);
        __builtin_amdgcn_global_load_lds((const __attribute__((address_space(1))) void*)(A + (size_t)r2g * 1024 + s2),
            (__attribute__((address_space(3))) void*)(&alds[buf][g2 * 16]), 16, 0, 0);
        __builtin_amdgcn_global_load_lds((const __attribute__((address_space(1))) void*)(B + (size_t)r1 * 1024 + s1),
            (__attribute__((address_space(3))) void*)(&blds[buf][g1 * 16]), 16, 0, 0);
        __builtin_amdgcn_global_load_lds((const __attribute__((address_space(1))) void*)(B + (size_t)r2g * 1024 + s2),
            (__attribute__((address_space(3))) void*)(&blds[buf][g2 * 16]), 16, 0, 0);
    };

    STAGE(0, 0);
    for (int ks = 0; ks < 16; ++ks) {
        const int cur = ks & 1;
        if (ks < 15) {
            STAGE(cur ^ 1, (ks + 1) * 32);
            asm volatile("s_waitcnt vmcnt(4)" ::: "memory");
        } else {
            asm volatile("s_waitcnt vmcnt(0)" ::: "memory");
        }
        __builtin_amdgcn_s_barrier();
        asm volatile("" ::: "memory");
        s16x8 af[4], bf[4];
        #pragma unroll
        for (int mi = 0; mi < 4; ++mi) {
            int row = wr * 64 + mi * 16 + lr;
            af[mi] = *(const s16x8*)(&alds[cur][row * 64 + ((lg ^ (lr & 3)) << 4)]);
        }
        #pragma unroll
        for (int ni = 0; ni < 4; ++ni) {
            int row = wc * 64 + ni * 16 + lr;
            bf[ni] = *(const s16x8*)(&blds[cur][row * 64 + ((lg ^ (lr & 3)) << 4)]);
        }
        __builtin_amdgcn_s_setprio(1);
        #pragma unroll
        for (int mi = 0; mi < 4; ++mi)
            #pragma unroll
            for (int ni = 0; ni < 4; ++ni)
                acc[mi][ni] = __builtin_amdgcn_mfma_f32_16x16x32_bf16(af[mi], bf[ni], acc[mi][ni], 0, 0, 0);
        __builtin_amdgcn_s_setprio(0);
        asm volatile("" ::: "memory");
        __builtin_amdgcn_s_barrier();
    }

    #pragma unroll
    for (int ni = 0; ni < 4; ++ni) {
        int cg = c0 + wc * 64 + ni * 16 + lr;
        float bb = bp[cg];
        #pragma unroll
        for (int mi = 0; mi < 4; ++mi) {
            int row = m0 + wr * 64 + mi * 16 + lg * 4;
            #pragma unroll
            for (int r2 = 0; r2 < 4; ++r2) {
                size_t idx = (size_t)(row + r2) * 512 + cg;
                out[idx] = acc[mi][ni][r2] + bb + x[idx];
            }
        }
    }
}

extern "C" void kernel_launch(void* const* d_in, const int* in_sizes, int n_in,
                              void* d_out, int out_size, void* d_ws, size_t ws_size,
                              hipStream_t stream) {
    (void)in_sizes; (void)n_in; (void)out_size; (void)ws_size;
    const float* x     = (const float*)d_in[0];
    const float* gamma = (const float*)d_in[1];
    const float* beta  = (const float*)d_in[2];
    const float* wq    = (const float*)d_in[3];
    const float* bq    = (const float*)d_in[4];
    const float* wk    = (const float*)d_in[5];
    const float* bk    = (const float*)d_in[6];
    const float* wv    = (const float*)d_in[7];
    const float* bv    = (const float*)d_in[8];
    const float* wp    = (const float*)d_in[9];
    const float* bp    = (const float*)d_in[10];
    float* out = (float*)d_out;

    char* ws = (char*)d_ws;
    ushort_t* wt    = (ushort_t*)(ws);                 // 2 MB
    float*    stats = (float*)(ws + (2ull<<20));       // 1 KB
    ushort_t* xn    = (ushort_t*)(ws + (4ull<<20));    // 16 MB
    ushort_t* qb    = (ushort_t*)(ws + (20ull<<20));   // 16 MB
    ushort_t* kb    = (ushort_t*)(ws + (36ull<<20));   // 16 MB
    ushort_t* vt    = (ushort_t*)(ws + (52ull<<20));   // 16 MB
    ushort_t* Ob    = (ushort_t*)(ws + (68ull<<20));   // 16 MB

    hipLaunchKernelGGL(wconv_kernel,    dim3(4096),       dim3(256), 0, stream, wq, wk, wv, wp, wt);
    hipLaunchKernelGGL(gn_stats_kernel, dim3(128),        dim3(256), 0, stream, x, stats);
    hipLaunchKernelGGL(gn_norm_kernel,  dim3(8192),       dim3(256), 0, stream, x, gamma, beta, stats, xn);
    hipLaunchKernelGGL(qkv_kernel,      dim3(128, 12),    dim3(256), 0, stream, xn, wt, bq, bk, bv, qb, kb, vt);
    hipLaunchKernelGGL(attn_kernel,     dim3(64, 4),      dim3(256), 0, stream, qb, kb, vt, Ob);
    hipLaunchKernelGGL(proj_kernel,     dim3(128, 4),     dim3(256), 0, stream, Ob, wt, bp, x, out);
}

// Round 17
// 333.371 us; speedup vs baseline: 1.2603x; 1.1444x over previous
//
#include <hip/hip_runtime.h>
#include <hip/hip_bf16.h>

typedef __attribute__((ext_vector_type(4))) float f32x4;
typedef __attribute__((ext_vector_type(8))) short s16x8;
typedef unsigned short ushort_t;

#define N_DIM 4096
#define C_DIM 512

#if __has_builtin(__builtin_amdgcn_exp2f)
#define EXP2(x) __builtin_amdgcn_exp2f(x)
#else
#define EXP2(x) exp2f(x)
#endif

static __device__ __forceinline__ unsigned short f2bf(float f) {
    union { float f; unsigned u; } v; v.f = f;
    unsigned r = v.u + 0x7FFFu + ((v.u >> 16) & 1u);
    return (unsigned short)(r >> 16);
}

// ---------------- GroupNorm stats
__global__ void gn_stats_kernel(const float* __restrict__ x, float* __restrict__ stats) {
    int bg = blockIdx.x;
    int b = bg >> 5, g = bg & 31;
    const float* base = x + (size_t)b * (N_DIM * C_DIM) + g * 16;
    float sum = 0.f, ss = 0.f;
    for (int n = threadIdx.x; n < N_DIM; n += 256) {
        const float4* p = (const float4*)(base + (size_t)n * C_DIM);
        #pragma unroll
        for (int t = 0; t < 4; ++t) {
            float4 v = p[t];
            sum += v.x + v.y + v.z + v.w;
            ss  += v.x*v.x + v.y*v.y + v.z*v.z + v.w*v.w;
        }
    }
    #pragma unroll
    for (int o = 32; o > 0; o >>= 1) {
        sum += __shfl_down(sum, o);
        ss  += __shfl_down(ss, o);
    }
    __shared__ float red[8];
    int wid = threadIdx.x >> 6, lane = threadIdx.x & 63;
    if (lane == 0) { red[wid*2] = sum; red[wid*2+1] = ss; }
    __syncthreads();
    if (threadIdx.x == 0) {
        sum = red[0]+red[2]+red[4]+red[6];
        ss  = red[1]+red[3]+red[5]+red[7];
        float mean = sum * (1.f/65536.f);
        float var  = ss  * (1.f/65536.f) - mean*mean;
        stats[bg*2]   = mean;
        stats[bg*2+1] = rsqrtf(var + 1e-5f);
    }
}

// ---------------- normalize + gamma/beta + cast to bf16
__global__ void gn_norm_kernel(const float* __restrict__ x, const float* __restrict__ gamma,
                               const float* __restrict__ beta, const float* __restrict__ stats,
                               ushort_t* __restrict__ xn) {
    size_t i = ((size_t)blockIdx.x * 256 + threadIdx.x) * 4;
    int c = (int)(i & 511);
    int b = (int)(i >> 21);
    int bg = b*32 + (c >> 4);
    float mean = stats[bg*2], rstd = stats[bg*2+1];
    float4 v  = *(const float4*)(x + i);
    float4 ga = *(const float4*)(gamma + c);
    float4 be = *(const float4*)(beta + c);
    ushort4 o;
    o.x = f2bf((v.x - mean) * rstd * ga.x + be.x);
    o.y = f2bf((v.y - mean) * rstd * ga.y + be.y);
    o.z = f2bf((v.z - mean) * rstd * ga.z + be.z);
    o.w = f2bf((v.w - mean) * rstd * ga.w + be.w);
    *(ushort4*)(xn + i) = o;
}

// ---------------- weights: fp32 [Cin][Cout] -> bf16 transposed [Cout][Cin], 4 mats
__global__ void wconv_kernel(const float* __restrict__ wq, const float* __restrict__ wk,
                             const float* __restrict__ wv, const float* __restrict__ wp,
                             ushort_t* __restrict__ wt) {
    int idx = blockIdx.x * 256 + threadIdx.x;
    int m = idx >> 18;
    int r = idx & 262143;
    int ci = r >> 9, co = r & 511;
    const float* w = (m == 0) ? wq : (m == 1) ? wk : (m == 2) ? wv : wp;
    wt[(size_t)m * 262144 + (size_t)co * 512 + ci] = f2bf(w[(size_t)ci * 512 + co]);
}

// ---------------- QKV GEMM, m97-style 128x128 tile (verified R9-R14).
// q pre-scale folds C^-0.5 * log2(e) (exp2-domain softmax downstream).
__global__ __launch_bounds__(256) void qkv_kernel(const ushort_t* __restrict__ xn, const ushort_t* __restrict__ wt,
                         const float* __restrict__ bq, const float* __restrict__ bk, const float* __restrict__ bv,
                         ushort_t* __restrict__ q, ushort_t* __restrict__ k, ushort_t* __restrict__ v) {
    __shared__ char alds[2][8192];
    __shared__ char blds[2][8192];
    const int tid = threadIdx.x;
    const int w = tid >> 6, lane = tid & 63;
    const int lr = lane & 15, lg = lane >> 4;
    const int wr = w >> 1, wc = w & 1;
    const int m0 = blockIdx.x * 128;
    const int c0g = blockIdx.y * 128;
    const int z = c0g >> 9;
    const int c0 = c0g & 511;
    const ushort_t* W = wt + (size_t)z * 262144;
    const float* bias = (z == 0) ? bq : (z == 1) ? bk : bv;
    const float scale = (z == 0) ? 0.06376257818f : 1.0f;  // 512^-0.5 * log2(e)

    f32x4 acc[4][4];
    #pragma unroll
    for (int a = 0; a < 4; ++a)
        #pragma unroll
        for (int b = 0; b < 4; ++b) acc[a][b] = (f32x4){0.f,0.f,0.f,0.f};

    const int g1 = tid, g2 = tid + 256;
    const int r1 = g1 >> 2, s1 = ((g1 & 3) ^ (r1 & 3)) << 4;
    const int r2g = g2 >> 2, s2 = ((g2 & 3) ^ (r2g & 3)) << 4;

    auto STAGE = [&](int buf, int k0) {
        const char* A = (const char*)xn + (size_t)(m0) * 1024 + k0 * 2;
        const char* B = (const char*)W + (size_t)(c0) * 1024 + k0 * 2;
        __builtin_amdgcn_global_load_lds((const __attribute__((address_space(1))) void*)(A + (size_t)r1 * 1024 + s1),
            (__attribute__((address_space(3))) void*)(&alds[buf][g1 * 16]), 16, 0, 0);
        __builtin_amdgcn_global_load_lds((const __attribute__((address_space(1))) void*)(A + (size_t)r2g * 1024 + s2),
            (__attribute__((address_space(3))) void*)(&alds[buf][g2 * 16]), 16, 0, 0);
        __builtin_amdgcn_global_load_lds((const __attribute__((address_space(1))) void*)(B + (size_t)r1 * 1024 + s1),
            (__attribute__((address_space(3))) void*)(&blds[buf][g1 * 16]), 16, 0, 0);
        __builtin_amdgcn_global_load_lds((const __attribute__((address_space(1))) void*)(B + (size_t)r2g * 1024 + s2),
            (__attribute__((address_space(3))) void*)(&blds[buf][g2 * 16]), 16, 0, 0);
    };

    STAGE(0, 0);
    for (int ks = 0; ks < 16; ++ks) {
        const int cur = ks & 1;
        if (ks < 15) {
            STAGE(cur ^ 1, (ks + 1) * 32);
            asm volatile("s_waitcnt vmcnt(4)" ::: "memory");
        } else {
            asm volatile("s_waitcnt vmcnt(0)" ::: "memory");
        }
        __builtin_amdgcn_s_barrier();
        asm volatile("" ::: "memory");
        s16x8 af[4], bf[4];
        #pragma unroll
        for (int mi = 0; mi < 4; ++mi) {
            int row = wr * 64 + mi * 16 + lr;
            af[mi] = *(const s16x8*)(&alds[cur][row * 64 + ((lg ^ (lr & 3)) << 4)]);
        }
        #pragma unroll
        for (int ni = 0; ni < 4; ++ni) {
            int row = wc * 64 + ni * 16 + lr;
            bf[ni] = *(const s16x8*)(&blds[cur][row * 64 + ((lg ^ (lr & 3)) << 4)]);
        }
        #pragma unroll
        for (int mi = 0; mi < 4; ++mi)
            #pragma unroll
            for (int ni = 0; ni < 4; ++ni)
                acc[mi][ni] = __builtin_amdgcn_mfma_f32_16x16x32_bf16(af[mi], bf[ni], acc[mi][ni], 0, 0, 0);
        asm volatile("" ::: "memory");
        __builtin_amdgcn_s_barrier();
    }

    if (z < 2) {
        ushort_t* out = (z == 0) ? q : k;
        #pragma unroll
        for (int ni = 0; ni < 4; ++ni) {
            int cg = c0 + wc * 64 + ni * 16 + lr;
            float bb = bias[cg];
            #pragma unroll
            for (int mi = 0; mi < 4; ++mi) {
                int row = m0 + wr * 64 + mi * 16 + lg * 4;
                #pragma unroll
                for (int r2 = 0; r2 < 4; ++r2)
                    out[(size_t)(row + r2) * 512 + cg] = f2bf((acc[mi][ni][r2] + bb) * scale);
            }
        }
    } else {
        #pragma unroll
        for (int ni = 0; ni < 4; ++ni) {
            int cg = c0 + wc * 64 + ni * 16 + lr;
            float bb = bias[cg];
            #pragma unroll
            for (int mi = 0; mi < 4; ++mi) {
                int row = m0 + wr * 64 + mi * 16 + lg * 4;
                int batch = row >> 12, j = row & 4095;
                ushort4 o;
                o.x = f2bf(acc[mi][ni][0] + bb);
                o.y = f2bf(acc[mi][ni][1] + bb);
                o.z = f2bf(acc[mi][ni][2] + bb);
                o.w = f2bf(acc[mi][ni][3] + bb);
                *(ushort4*)(v + (size_t)batch * (512*4096) + (size_t)cg * 4096 + j) = o;
            }
        }
    }
}

// ---------------- flash attention (R14 best: one barrier/iter, QKSM(t+1)-first,
// 8-slot K swizzle via hoisted bases + imm offsets, exp2 softmax, max3/sum trees).
__global__ __launch_bounds__(256) void attn_kernel(const ushort_t* __restrict__ q, const ushort_t* __restrict__ k,
                          const ushort_t* __restrict__ vt, ushort_t* __restrict__ O) {
    __shared__ char slds[131072 + 8192 + 512];  // 2x(K32K|V32K) | plds x2 | rlds x2
    char* plds = slds + 131072;
    float* rlds = (float*)(slds + 131072 + 8192);
    const int tid = threadIdx.x;
    const int w = tid >> 6, lane = tid & 63;
    const int lr = lane & 15, lg = lane >> 4;
    const int batch = blockIdx.y;
    const int i0 = blockIdx.x * 64;
    const char* kb = (const char*)(k  + (size_t)batch * (4096 * 512));
    const char* vb = (const char*)(vt + (size_t)batch * (512 * 4096));
    const ushort_t* qb = q + (size_t)batch * (4096 * 512);

    s16x8 qf[16];
    {
        const ushort_t* qrow = qb + (size_t)(i0 + w * 16 + lr) * 512 + lg * 8;
        #pragma unroll
        for (int t = 0; t < 16; ++t) qf[t] = *(const s16x8*)(qrow + t * 32);
    }

    f32x4 acc[8][4];
    #pragma unroll
    for (int a = 0; a < 8; ++a)
        #pragma unroll
        for (int b = 0; b < 4; ++b) acc[a][b] = (f32x4){0.f,0.f,0.f,0.f};
    float m = -1e30f, s = 0.f;

    // hoisted per-lane LDS bases. K-read: R12's 8-slot swizzle decomposed:
    // addr(tt) = kbase_e/o + (tt>>1)*128  (e: even tt, o: odd tt; o = e ^ 64)
    const int kbase_e = lr * 1024 + ((lg ^ (lr & 3)) << 4) + (((lr >> 2) & 1) << 6);
    const int kbase_o = kbase_e ^ 64;
    const int vread_off = 32768 + w * 8192 + lr * 64 + ((lg ^ ((lr >> 1) & 3)) << 4); // + ct*1024
    const int pread_off = lr * 64 + ((lg ^ (lr & 3)) << 4);                           // + g*1024
    const int vswz = ((lane & 3) ^ ((lane >> 3) & 3)) << 4;

    auto STAGE_K = [&](int buf, int j0) {
        char* lb = slds + buf * 65536;
        const char* gk = kb + (size_t)j0 * 1024;
        #pragma unroll
        for (int r = 0; r < 8; ++r) {
            int row = w * 8 + r;             // row&7 == r  (8-slot involution, rule 21)
            __builtin_amdgcn_global_load_lds(
                (const __attribute__((address_space(1))) void*)(gk + (size_t)row * 1024 + ((lane ^ r) << 4)),
                (__attribute__((address_space(3))) void*)(lb + row * 1024), 16, 0, 0);
        }
    };
    auto STAGE_V = [&](int buf, int j0) {
        char* lv = slds + buf * 65536 + 32768;
        const char* gv = vb + (size_t)j0 * 2;
        #pragma unroll
        for (int r = 0; r < 8; ++r) {
            int p = w * 8 + r;
            int c = p * 16 + (lane >> 2);
            __builtin_amdgcn_global_load_lds(
                (const __attribute__((address_space(1))) void*)(gv + (size_t)c * 8192 + vswz),
                (__attribute__((address_space(3))) void*)(lv + p * 1024), 16, 0, 0);
        }
    };

    auto QKSM = [&](int buf, int pbuf) {
        const char* ke = slds + buf * 65536 + kbase_e;
        const char* ko = slds + buf * 65536 + kbase_o;
        f32x4 sa = {0,0,0,0}, sb = {0,0,0,0}, sc2 = {0,0,0,0}, sd = {0,0,0,0};
        #pragma unroll
        for (int tt = 0; tt < 16; tt += 2) {
            const int off = (tt >> 1) * 128;
            s16x8 k0f = *(const s16x8*)(ke + off);
            s16x8 k1f = *(const s16x8*)(ko + off);
            s16x8 k2f = *(const s16x8*)(ke + 16384 + off);
            s16x8 k3f = *(const s16x8*)(ko + 16384 + off);
            sa  = __builtin_amdgcn_mfma_f32_16x16x32_bf16(k0f, qf[tt],   sa,  0,0,0);
            sb  = __builtin_amdgcn_mfma_f32_16x16x32_bf16(k1f, qf[tt+1], sb,  0,0,0);
            sc2 = __builtin_amdgcn_mfma_f32_16x16x32_bf16(k2f, qf[tt],   sc2, 0,0,0);
            sd  = __builtin_amdgcn_mfma_f32_16x16x32_bf16(k3f, qf[tt+1], sd,  0,0,0);
        }
        f32x4 s1 = sa + sb;   // log2-domain scores
        f32x4 s2 = sc2 + sd;

        float m01 = fmaxf(fmaxf(s1[0], s1[1]), s1[2]);
        float m02 = fmaxf(fmaxf(s1[3], s2[0]), s2[1]);
        float m03 = fmaxf(fmaxf(s2[2], s2[3]), m01);
        float tm = fmaxf(m02, m03);
        tm = fmaxf(tm, __shfl_xor(tm, 16));
        tm = fmaxf(tm, __shfl_xor(tm, 32));
        float resc = 1.f;
        if (!__all(tm <= m + 11.0f)) {       // defer-max, log2 units
            float mnew = fmaxf(m, tm);
            resc = EXP2(m - mnew);
            s *= resc;
            m = mnew;
        }
        f32x4 p1, p2;
        #pragma unroll
        for (int r2 = 0; r2 < 4; ++r2) { p1[r2] = EXP2(s1[r2] - m); p2[r2] = EXP2(s2[r2] - m); }
        float t0 = (p1[0] + p1[1]) + (p1[2] + p1[3]);
        float t1 = (p2[0] + p2[1]) + (p2[2] + p2[3]);
        float ts = t0 + t1;
        ts += __shfl_xor(ts, 16);
        ts += __shfl_xor(ts, 32);
        s += ts;

        unsigned w0 = (unsigned)f2bf(p1[0]) | ((unsigned)f2bf(p1[1]) << 16);
        unsigned w1 = (unsigned)f2bf(p1[2]) | ((unsigned)f2bf(p1[3]) << 16);
        unsigned w2 = (unsigned)f2bf(p2[0]) | ((unsigned)f2bf(p2[1]) << 16);
        unsigned w3 = (unsigned)f2bf(p2[2]) | ((unsigned)f2bf(p2[3]) << 16);
        char* prow = plds + pbuf * 4096 + w * 1024 + lr * 64 + ((lg & 1) << 3);
        *(uint2*)(prow + ((((lg >> 1)    ) ^ (lr & 3)) << 4)) = (uint2){w0, w1};
        *(uint2*)(prow + (((2 | (lg >> 1)) ^ (lr & 3)) << 4)) = (uint2){w2, w3};
        if (lg == 0) rlds[pbuf * 64 + w * 16 + lr] = resc;
    };

    // prologue: K(0),V(0) -> buf0; K(1) -> buf1; FULL drain
    STAGE_K(0, 0);
    STAGE_V(0, 0);
    STAGE_K(1, 32);
    asm volatile("s_waitcnt vmcnt(0)" ::: "memory");
    __builtin_amdgcn_s_barrier();
    asm volatile("" ::: "memory");
    QKSM(0, 0);
    asm volatile("s_waitcnt lgkmcnt(0)" ::: "memory");
    __builtin_amdgcn_s_barrier();
    asm volatile("" ::: "memory");

    for (int t = 0; t < 128; ++t) {
        const int cur = t & 1, nxt = cur ^ 1;
        if (t < 126) STAGE_K(cur, (t + 2) * 32);
        if (t < 127) STAGE_V(nxt, (t + 1) * 32);

        // QK(t+1) + softmax + P(t+1) publish FIRST (long serial chain starts early)
        if (t < 127) QKSM(nxt, nxt);

        // rescale + P fragments + PV(t)
        {
            const float* rr = rlds + cur * 64;
            float rf0 = rr[lr], rf1 = rr[16 + lr], rf2 = rr[32 + lr], rf3 = rr[48 + lr];
            if (__any(rf0 != 1.f || rf1 != 1.f || rf2 != 1.f || rf3 != 1.f)) {
                #pragma unroll
                for (int ct = 0; ct < 8; ++ct) {
                    acc[ct][0] *= rf0; acc[ct][1] *= rf1; acc[ct][2] *= rf2; acc[ct][3] *= rf3;
                }
            }
        }
        const char* pb = plds + cur * 4096 + pread_off;
        s16x8 pf[4];
        #pragma unroll
        for (int g = 0; g < 4; ++g)
            pf[g] = *(const s16x8*)(pb + g * 1024);

        const char* vl = slds + cur * 65536 + vread_off;
        #pragma unroll
        for (int ct = 0; ct < 8; ++ct) {
            s16x8 vf = *(const s16x8*)(vl + ct * 1024);
            #pragma unroll
            for (int g = 0; g < 4; ++g)
                acc[ct][g] = __builtin_amdgcn_mfma_f32_16x16x32_bf16(vf, pf[g], acc[ct][g], 0,0,0);
        }

        asm volatile("s_waitcnt vmcnt(0) lgkmcnt(0)" ::: "memory");
        __builtin_amdgcn_s_barrier();
        asm volatile("" ::: "memory");
    }

    // final 1/s exchange
    if (lg == 0) rlds[w * 16 + lr] = 1.f / s;
    __syncthreads();
    float inv0 = rlds[lr], inv1 = rlds[16 + lr], inv2 = rlds[32 + lr], inv3 = rlds[48 + lr];
    #pragma unroll
    for (int ct = 0; ct < 8; ++ct) {
        #pragma unroll
        for (int g = 0; g < 4; ++g) {
            float iv = (g == 0) ? inv0 : (g == 1) ? inv1 : (g == 2) ? inv2 : inv3;
            ushort4 o;
            o.x = f2bf(acc[ct][g][0] * iv);
            o.y = f2bf(acc[ct][g][1] * iv);
            o.z = f2bf(acc[ct][g][2] * iv);
            o.w = f2bf(acc[ct][g][3] * iv);
            *(ushort4*)(O + ((size_t)batch * 4096 + i0 + g*16 + lr) * 512
                        + w * 128 + ct * 16 + lg * 4) = o;
        }
    }
}

// ---------------- final projection, m97-style 128x128 tile + bias + residual (fp32 out)
__global__ __launch_bounds__(256) void proj_kernel(const ushort_t* __restrict__ O, const ushort_t* __restrict__ wt,
                          const float* __restrict__ bp, const float* __restrict__ x, float* __restrict__ out) {
    __shared__ char alds[2][8192];
    __shared__ char blds[2][8192];
    const int tid = threadIdx.x;
    const int w = tid >> 6, lane = tid & 63;
    const int lr = lane & 15, lg = lane >> 4;
    const int wr = w >> 1, wc = w & 1;
    const int m0 = blockIdx.x * 128;
    const int c0 = blockIdx.y * 128;
    const ushort_t* W = wt + (size_t)3 * 262144;

    f32x4 acc[4][4];
    #pragma unroll
    for (int a = 0; a < 4; ++a)
        #pragma unroll
        for (int b = 0; b < 4; ++b) acc[a][b] = (f32x4){0.f,0.f,0.f,0.f};

    const int g1 = tid, g2 = tid + 256;
    const int r1 = g1 >> 2, s1 = ((g1 & 3) ^ (r1 & 3)) << 4;
    const int r2g = g2 >> 2, s2 = ((g2 & 3) ^ (r2g & 3)) << 4;

    auto STAGE = [&](int buf, int k0) {
        const char* A = (const char*)O + (size_t)(m0) * 1024 + k0 * 2;
        const char* B = (const char*)W + (size_t)(c0) * 1024 + k0 * 2;
        __builtin_amdgcn_global_load_lds((const __attribute__((address_space(1))) void*)(A + (size_t)r1 * 1024 + s1),
            (__attribute__((address_space(3))) void*)(&alds[buf][g1 * 16]), 16, 0, 0);
        __builtin_amdgcn_global_load_lds((const __attribute__((address_space(1))) void*)(A + (size_t)r2g * 1024 + s2),
            (__attribute__((address_space(3))) void*)(&alds[buf][g2 * 16]), 16, 0, 0);
        __builtin_amdgcn_global_load_lds((const __attribute__((address_space(1))) void*)(B + (size_t)r1 * 1024 + s1),
            (__attribute__((address_space(3))) void*)(&blds[buf][g1 * 16]), 16, 0, 0);
        __builtin_amdgcn_global_load_lds((const __attribute__((address_space(1))) void*)(B + (size_t)r2g * 1024 + s2),
            (__attribute__((address_space(3))) void*)(&blds[buf][g2 * 16]), 16, 0, 0);
    };

    STAGE(0, 0);
    for (int ks = 0; ks < 16; ++ks) {
        const int cur = ks & 1;
        if (ks < 15) {
            STAGE(cur ^ 1, (ks + 1) * 32);
            asm volatile("s_waitcnt vmcnt(4)" ::: "memory");
        } else {
            asm volatile("s_waitcnt vmcnt(0)" ::: "memory");
        }
        __builtin_amdgcn_s_barrier();
        asm volatile("" ::: "memory");
        s16x8 af[4], bf[4];
        #pragma unroll
        for (int mi = 0; mi < 4; ++mi) {
            int row = wr * 64 + mi * 16 + lr;
            af[mi] = *(const s16x8*)(&alds[cur][row * 64 + ((lg ^ (lr & 3)) << 4)]);
        }
        #pragma unroll
        for (int ni = 0; ni < 4; ++ni) {
            int row = wc * 64 + ni * 16 + lr;
            bf[ni] = *(const s16x8*)(&blds[cur][row * 64 + ((lg ^ (lr & 3)) << 4)]);
        }
        #pragma unroll
        for (int mi = 0; mi < 4; ++mi)
            #pragma unroll
            for (int ni = 0; ni < 4; ++ni)
                acc[mi][ni] = __builtin_amdgcn_mfma_f32_16x16x32_bf16(af[mi], bf[ni], acc[mi][ni], 0, 0, 0);
        asm volatile("" ::: "memory");
        __builtin_amdgcn_s_barrier();
    }

    #pragma unroll
    for (int ni = 0; ni < 4; ++ni) {
        int cg = c0 + wc * 64 + ni * 16 + lr;
        float bb = bp[cg];
        #pragma unroll
        for (int mi = 0; mi < 4; ++mi) {
            int row = m0 + wr * 64 + mi * 16 + lg * 4;
            #pragma unroll
            for (int r2 = 0; r2 < 4; ++r2) {
                size_t idx = (size_t)(row + r2) * 512 + cg;
                out[idx] = acc[mi][ni][r2] + bb + x[idx];
            }
        }
    }
}

extern "C" void kernel_launch(void* const* d_in, const int* in_sizes, int n_in,
                              void* d_out, int out_size, void* d_ws, size_t ws_size,
                              hipStream_t stream) {
    (void)in_sizes; (void)n_in; (void)out_size; (void)ws_size;
    const float* x     = (const float*)d_in[0];
    const float* gamma = (const float*)d_in[1];
    const float* beta  = (const float*)d_in[2];
    const float* wq    = (const float*)d_in[3];
    const float* bq    = (const float*)d_in[4];
    const float* wk    = (const float*)d_in[5];
    const float* bk    = (const float*)d_in[6];
    const float* wv    = (const float*)d_in[7];
    const float* bv    = (const float*)d_in[8];
    const float* wp    = (const float*)d_in[9];
    const float* bp    = (const float*)d_in[10];
    float* out = (float*)d_out;

    char* ws = (char*)d_ws;
    ushort_t* wt    = (ushort_t*)(ws);                 // 2 MB
    float*    stats = (float*)(ws + (2ull<<20));       // 1 KB
    ushort_t* xn    = (ushort_t*)(ws + (4ull<<20));    // 16 MB
    ushort_t* qb    = (ushort_t*)(ws + (20ull<<20));   // 16 MB
    ushort_t* kb    = (ushort_t*)(ws + (36ull<<20));   // 16 MB
    ushort_t* vt    = (ushort_t*)(ws + (52ull<<20));   // 16 MB
    ushort_t* Ob    = (ushort_t*)(ws + (68ull<<20));   // 16 MB

    hipLaunchKernelGGL(wconv_kernel,    dim3(4096),       dim3(256), 0, stream, wq, wk, wv, wp, wt);
    hipLaunchKernelGGL(gn_stats_kernel, dim3(128),        dim3(256), 0, stream, x, stats);
    hipLaunchKernelGGL(gn_norm_kernel,  dim3(8192),       dim3(256), 0, stream, x, gamma, beta, stats, xn);
    hipLaunchKernelGGL(qkv_kernel,      dim3(128, 12),    dim3(256), 0, stream, xn, wt, bq, bk, bv, qb, kb, vt);
    hipLaunchKernelGGL(attn_kernel,     dim3(64, 4),      dim3(256), 0, stream, qb, kb, vt, Ob);
    hipLaunchKernelGGL(proj_kernel,     dim3(128, 4),     dim3(256), 0, stream, Ob, wt, bp, x, out);
}